// Round 14
// baseline (134.458 us; speedup 1.0000x reference)
//
#include <hip/hip_runtime.h>

// Problem constants (fixed by the reference file).
#define T_LEN 8192
#define D_CH  2048
#define D2    (D_CH / 2)          // channel pairs
#define CC    256                 // chunks along T
#define L_C   (T_LEN / CC)        // 32 steps per chunk

// Native clang vector types: __builtin_nontemporal_store requires these
// (HIP_vector_type float2/float4 are rejected).
typedef float vf2 __attribute__((ext_vector_type(2)));
typedef float vf4 __attribute__((ext_vector_type(4)));

// v = z*v + x (x real), z complex.
__device__ __forceinline__ void step_real(float zre, float zim,
                                          float& vre, float& vim, float x) {
    float nre = fmaf(zre, vre, fmaf(-zim, vim, x));
    float nim = fmaf(zre, vim, zim * vre);
    vre = nre; vim = nim;
}

__device__ __forceinline__ void load_z(const float* __restrict__ size_,
                                       const float* __restrict__ theta_,
                                       int d, float& zre, float& zim) {
    float e = expf(size_[d]);
    float r = expf(-e);
    float s, c;
    sincosf(theta_[d], &s, &c);
    zre = r * c;
    zim = r * s;
}

__device__ __forceinline__ void load_zL(const float* __restrict__ size_,
                                        const float* __restrict__ theta_,
                                        int d, float& zLre, float& zLim) {
    float e  = expf(size_[d]);
    float rL = expf(-(float)L_C * e);          // underflow->0 is correct
    float sL, cL;
    sincosf((float)L_C * theta_[d], &sL, &cL);
    zLre = rL * cL;
    zLim = rL * sL;
}

// Kernel 1: per (chunk, channel-pair) local scan from v=0; publish ONLY the
// chunk-final complex values. 64 MB coalesced float2 read.
__global__ __launch_bounds__(256) void k_sums(const float* __restrict__ x,
                                              const float* __restrict__ size_,
                                              const float* __restrict__ theta_,
                                              float4* __restrict__ sums) {
    const int dp = blockIdx.x * 256 + threadIdx.x;   // channel pair
    const int d  = dp * 2;
    const int c  = blockIdx.y;

    float zre0, zim0, zre1, zim1;
    load_z(size_, theta_, d,     zre0, zim0);
    load_z(size_, theta_, d + 1, zre1, zim1);

    const float2* xp = (const float2*)x + (size_t)c * L_C * D2 + dp;
    float vre0 = 0.f, vim0 = 0.f, vre1 = 0.f, vim1 = 0.f;
#pragma unroll 16
    for (int k = 0; k < L_C; ++k) {
        float2 xv = xp[(size_t)k * D2];
        step_real(zre0, zim0, vre0, vim0, xv.x);
        step_real(zre1, zim1, vre1, vim1, xv.y);
    }
    sums[(size_t)c * D2 + dp] = make_float4(vre0, vim0, vre1, vim1);
}

// Kernel 2: block (c) computes its carry prefix BACKWARD over sums[c-1..0]
// with multiplier mult *= z^L per hop; mult underflows to exactly 0 within a
// few batches (exact: dropped terms are exactly zero), wave-uniform break.
// Then scans its chunk seeded with the carry, re-reading x (L3-warm from k1),
// streaming the output with nontemporal stores. 2 channels per thread.
template <bool ILV>
__global__ __launch_bounds__(256) void k_scan(const float* __restrict__ x,
                                              const float* __restrict__ size_,
                                              const float* __restrict__ theta_,
                                              const float4* __restrict__ sums,
                                              float* __restrict__ out) {
    const int dp = blockIdx.x * 256 + threadIdx.x;
    const int d  = dp * 2;
    const int c  = blockIdx.y;

    float zre0, zim0, zre1, zim1;
    load_z(size_, theta_, d,     zre0, zim0);
    load_z(size_, theta_, d + 1, zre1, zim1);
    float zLre0, zLim0, zLre1, zLim1;
    load_zL(size_, theta_, d,     zLre0, zLim0);
    load_zL(size_, theta_, d + 1, zLre1, zLim1);

    // Backward prefix with exact-zero early exit (per channel pair).
    float cre0 = 0.f, cim0 = 0.f, cre1 = 0.f, cim1 = 0.f;
    float mre0 = 1.f, mim0 = 0.f, mre1 = 1.f, mim1 = 0.f;
    for (int j0 = c - 1; j0 >= 0; j0 -= 16) {          // c is block-uniform
        const int nb = (j0 + 1 < 16) ? (j0 + 1) : 16;  // block-uniform count
        float4 loc[16];
#pragma unroll
        for (int t = 0; t < 16; ++t)
            loc[t] = (t < nb) ? sums[(size_t)(j0 - t) * D2 + dp]
                              : make_float4(0.f, 0.f, 0.f, 0.f);
#pragma unroll
        for (int t = 0; t < 16; ++t) {
            if (t < nb) {                              // block-uniform branch
                cre0 = fmaf(mre0, loc[t].x, fmaf(-mim0, loc[t].y, cre0));
                cim0 = fmaf(mre0, loc[t].y, fmaf( mim0, loc[t].x, cim0));
                cre1 = fmaf(mre1, loc[t].z, fmaf(-mim1, loc[t].w, cre1));
                cim1 = fmaf(mre1, loc[t].w, fmaf( mim1, loc[t].z, cim1));
                float n0 = mre0 * zLre0 - mim0 * zLim0;
                float m0 = fmaf(mre0, zLim0, mim0 * zLre0);
                mre0 = n0; mim0 = m0;
                float n1 = mre1 * zLre1 - mim1 * zLim1;
                float m1 = fmaf(mre1, zLim1, mim1 * zLre1);
                mre1 = n1; mim1 = m1;
            }
        }
        if (__all(mre0 == 0.f && mim0 == 0.f && mre1 == 0.f && mim1 == 0.f))
            break;
    }

    // Scan the chunk seeded with the carry; nontemporal stream out.
    float vre0 = cre0, vim0 = cim0, vre1 = cre1, vim1 = cim1;
    const float2* xp = (const float2*)x + (size_t)c * L_C * D2 + dp;
    if (ILV) {
        vf4* o4 = (vf4*)out + (size_t)c * L_C * D2 + dp;
#pragma unroll 16
        for (int k = 0; k < L_C; ++k) {
            float2 xv = xp[(size_t)k * D2];
            step_real(zre0, zim0, vre0, vim0, xv.x);
            step_real(zre1, zim1, vre1, vim1, xv.y);
            vf4 v = { vre0, vim0, vre1, vim1 };
            __builtin_nontemporal_store(v, &o4[(size_t)k * D2]);
        }
    } else {
        vf2* o2 = (vf2*)out + (size_t)c * L_C * D2 + dp;
#pragma unroll 16
        for (int k = 0; k < L_C; ++k) {
            float2 xv = xp[(size_t)k * D2];
            step_real(zre0, zim0, vre0, vim0, xv.x);
            step_real(zre1, zim1, vre1, vim1, xv.y);
            vf2 v = { vre0, vre1 };
            __builtin_nontemporal_store(v, &o2[(size_t)k * D2]);
        }
    }
}

extern "C" void kernel_launch(void* const* d_in, const int* in_sizes, int n_in,
                              void* d_out, int out_size, void* d_ws, size_t ws_size,
                              hipStream_t stream) {
    const float* x  = (const float*)d_in[0];
    const float* sz = (const float*)d_in[1];
    const float* th = (const float*)d_in[2];
    float4* sums = (float4*)d_ws;                 // CC * D2 * 16 B = 4 MB
    float* out = (float*)d_out;
    const bool realOnly = (out_size == T_LEN * D_CH);

    dim3 blk(256);
    dim3 grid(D2 / 256, CC);                      // (4, 256) = 1024 blocks

    k_sums<<<grid, blk, 0, stream>>>(x, sz, th, sums);
    if (realOnly)
        k_scan<false><<<grid, blk, 0, stream>>>(x, sz, th, sums, out);
    else
        k_scan<true><<<grid, blk, 0, stream>>>(x, sz, th, sums, out);
}